// Round 6
// baseline (210.777 us; speedup 1.0000x reference)
//
#include <hip/hip_runtime.h>
#include <math.h>

#define N_SAMP 65536
#define DIM    512
#define NCLS   64
#define KSEL   64
#define SNBIN  4096

// workspace layout (bytes) — main path
#define OFF_COUNTS   0u          // 64 i32
#define OFF_CSUM     256u        // 64*512 f32 -> 131328
#define OFF_CENTERS  131328u     // cenb 64*512 bf16 -> 196864
#define OFF_C2       196864u     // 64 f32 -> 197120
#define OFF_MEANS    197120u     // 128 f32 -> 197632
#define OFF_DONE     197632u     // 1 u32
#define OFF_XB       262144u     // 65536*512 bf16 = 64 MB -> 67371008
#define OFF_DIST     67371008u   // 64*65536 f32 -> 84148224
#define WS_NEED      84148224u
#define OFF_DIST_FB  262144u     // fallback: dist right after header

typedef __attribute__((ext_vector_type(8))) short bf16x8;
typedef __attribute__((ext_vector_type(4))) float f32x4;

__device__ __forceinline__ unsigned short f2bf_rne(float f) {
  const unsigned u = __float_as_uint(f);
  return (unsigned short)((u + 0x7FFFu + ((u >> 16) & 1u)) >> 16);
}

// ---------------------------------------------------------------- init
__global__ __launch_bounds__(256) void k_init(int* __restrict__ counts,
                                              float* __restrict__ csum,
                                              unsigned* __restrict__ done) {
  const int i = blockIdx.x * 256 + threadIdx.x;
  const int stride = gridDim.x * 256;
  if (i < NCLS) counts[i] = 0;
  if (i == 0) *done = 0u;
  for (int j = i; j < NCLS * DIM; j += stride) csum[j] = 0.f;
}

// ------------------------------------------------- class partial sums (+ optional bf16 x emit)
__global__ __launch_bounds__(256) void k_class_sums(const float* __restrict__ x,
                                                    const int* __restrict__ y,
                                                    float* __restrict__ csum,
                                                    int* __restrict__ counts,
                                                    unsigned* __restrict__ xb32) {
  __shared__ int list[4096];
  __shared__ int lcnt;
  const int c  = blockIdx.x >> 4;
  const int r0 = (blockIdx.x & 15) * 4096;
  const int tid = threadIdx.x;
  if (tid == 0) lcnt = 0;
  __syncthreads();
  for (int i = tid; i < 4096; i += 256) {
    if (y[r0 + i] == c) { int p = atomicAdd(&lcnt, 1); list[p] = r0 + i; }
  }
  __syncthreads();
  const int n = lcnt;
  const int dbase = (tid >> 6) * 128 + (tid & 63) * 2;
  const int xoff = dbase >> 1;           // dword index within row (256 dwords of 2 bf16)
  float a0 = 0.f, a1 = 0.f, b0 = 0.f, b1 = 0.f;
  int i = 0;
  for (; i + 2 <= n; i += 2) {
    const int r0i = list[i], r1i = list[i + 1];
    const float* p0 = x + (size_t)r0i * DIM + dbase;
    const float* p1 = x + (size_t)r1i * DIM + dbase;
    const float v00 = p0[0], v01 = p0[1], v10 = p1[0], v11 = p1[1];
    a0 += v00; a1 += v01;
    b0 += v10; b1 += v11;
    if (xb32) {
      xb32[(size_t)r0i * 256 + xoff] = (unsigned)f2bf_rne(v00) | ((unsigned)f2bf_rne(v01) << 16);
      xb32[(size_t)r1i * 256 + xoff] = (unsigned)f2bf_rne(v10) | ((unsigned)f2bf_rne(v11) << 16);
    }
  }
  if (i < n) {
    const int ri = list[i];
    const float* p0 = x + (size_t)ri * DIM + dbase;
    const float v00 = p0[0], v01 = p0[1];
    a0 += v00; a1 += v01;
    if (xb32) xb32[(size_t)ri * 256 + xoff] = (unsigned)f2bf_rne(v00) | ((unsigned)f2bf_rne(v01) << 16);
  }
  a0 += b0; a1 += b1;
  atomicAdd(&csum[c * DIM + dbase], a0);
  atomicAdd(&csum[c * DIM + dbase + 1], a1);
  if (tid == 0) atomicAdd(&counts[c], n);
}

// ------------------------------------------------- finalize centers (bf16) + c2 (f32)
__global__ __launch_bounds__(64) void k_centers(const float* __restrict__ csum,
                                                const int* __restrict__ counts,
                                                unsigned short* __restrict__ cenb,
                                                float* __restrict__ c2) {
  const int c = blockIdx.x, l = threadIdx.x;
  const float inv = 1.0f / (float)counts[c];
  float ss = 0.f;
  #pragma unroll
  for (int j = 0; j < 8; ++j) {
    int d = j * 64 + l;
    float v = csum[c * DIM + d] * inv;
    cenb[c * DIM + d] = f2bf_rne(v);
    ss += v * v;
  }
  #pragma unroll
  for (int o = 32; o; o >>= 1) ss += __shfl_down(ss, o, 64);
  if (l == 0) c2[c] = ss;
}

// ------------------------------------------------- distances via bf16 MFMA, bf16 x input
#define CSTR 520
__global__ __launch_bounds__(512, 4) void k_dist_bf(const unsigned short* __restrict__ xb,
                                                    const unsigned short* __restrict__ cenb,
                                                    const float* __restrict__ c2,
                                                    float* __restrict__ dist) {
  __shared__ unsigned short cenS[NCLS * CSTR];
  __shared__ float c2s[NCLS];

  const int tid = threadIdx.x;
  const int wave = tid >> 6;
  const int lane = tid & 63;
  const int s0 = blockIdx.x * 128 + wave * 16;
  const int samp = s0 + (lane & 15);
  const int kg = lane >> 4;

  for (int q = tid; q < 4096; q += 512) {
    const int row = q >> 6, cc = q & 63;
    const uint4 v = *reinterpret_cast<const uint4*>(cenb + row * DIM + cc * 8);
    *reinterpret_cast<uint4*>(&cenS[row * CSTR + cc * 8]) = v;
  }
  if (tid < NCLS) c2s[tid] = c2[tid];
  __syncthreads();

  f32x4 acc[4] = {f32x4{0,0,0,0}, f32x4{0,0,0,0}, f32x4{0,0,0,0}, f32x4{0,0,0,0}};
  float x2 = 0.f;
  const unsigned short* __restrict__ xrow = xb + (size_t)samp * DIM + kg * 8;
  const int arow = lane & 15;

  #pragma unroll 4
  for (int s = 0; s < 16; ++s) {
    const int k0 = s * 32;
    const bf16x8 bfrag = *reinterpret_cast<const bf16x8*>(xrow + k0);
    const uint4 bu = *reinterpret_cast<const uint4*>(&bfrag);
    {
      const unsigned dw[4] = {bu.x, bu.y, bu.z, bu.w};
      #pragma unroll
      for (int q = 0; q < 4; ++q) {
        const float flo = __uint_as_float(dw[q] << 16);
        const float fhi = __uint_as_float(dw[q] & 0xFFFF0000u);
        x2 = fmaf(flo, flo, x2);
        x2 = fmaf(fhi, fhi, x2);
      }
    }
    const int kidx = k0 + kg * 8;
    const bf16x8 a0 = *reinterpret_cast<const bf16x8*>(&cenS[(arow +  0) * CSTR + kidx]);
    const bf16x8 a1 = *reinterpret_cast<const bf16x8*>(&cenS[(arow + 16) * CSTR + kidx]);
    const bf16x8 a2 = *reinterpret_cast<const bf16x8*>(&cenS[(arow + 32) * CSTR + kidx]);
    const bf16x8 a3 = *reinterpret_cast<const bf16x8*>(&cenS[(arow + 48) * CSTR + kidx]);
    acc[0] = __builtin_amdgcn_mfma_f32_16x16x32_bf16(a0, bfrag, acc[0], 0, 0, 0);
    acc[1] = __builtin_amdgcn_mfma_f32_16x16x32_bf16(a1, bfrag, acc[1], 0, 0, 0);
    acc[2] = __builtin_amdgcn_mfma_f32_16x16x32_bf16(a2, bfrag, acc[2], 0, 0, 0);
    acc[3] = __builtin_amdgcn_mfma_f32_16x16x32_bf16(a3, bfrag, acc[3], 0, 0, 0);
  }

  x2 += __shfl_xor(x2, 16, 64);
  x2 += __shfl_xor(x2, 32, 64);

  const int col = s0 + (lane & 15);
  #pragma unroll
  for (int t = 0; t < 4; ++t) {
    #pragma unroll
    for (int r = 0; r < 4; ++r) {
      const int cls = t * 16 + (lane >> 4) * 4 + r;
      const float d2 = c2s[cls] + x2 - 2.0f * acc[t][r];
      dist[(size_t)cls * N_SAMP + col] = sqrtf(fmaxf(d2, 1e-12f));
    }
  }
}

// ------------------------------------------------- fallback: fp32 x input (proven)
__global__ __launch_bounds__(512, 4) void k_dist_f32(const float* __restrict__ x,
                                                     const unsigned short* __restrict__ cenb,
                                                     const float* __restrict__ c2,
                                                     float* __restrict__ dist) {
  __shared__ unsigned short cenS[NCLS * CSTR];
  __shared__ float c2s[NCLS];
  const int tid = threadIdx.x;
  const int wave = tid >> 6;
  const int lane = tid & 63;
  const int s0 = blockIdx.x * 128 + wave * 16;
  const int samp = s0 + (lane & 15);
  const int kg = lane >> 4;
  for (int q = tid; q < 4096; q += 512) {
    const int row = q >> 6, cc = q & 63;
    const uint4 v = *reinterpret_cast<const uint4*>(cenb + row * DIM + cc * 8);
    *reinterpret_cast<uint4*>(&cenS[row * CSTR + cc * 8]) = v;
  }
  if (tid < NCLS) c2s[tid] = c2[tid];
  __syncthreads();
  f32x4 acc[4] = {f32x4{0,0,0,0}, f32x4{0,0,0,0}, f32x4{0,0,0,0}, f32x4{0,0,0,0}};
  float x2 = 0.f;
  const float* __restrict__ xrow = x + (size_t)samp * DIM + kg * 8;
  const int arow = lane & 15;
  #pragma unroll 4
  for (int s = 0; s < 16; ++s) {
    const int k0 = s * 32;
    float xf[8];
    *reinterpret_cast<float4*>(&xf[0]) = *reinterpret_cast<const float4*>(xrow + k0);
    *reinterpret_cast<float4*>(&xf[4]) = *reinterpret_cast<const float4*>(xrow + k0 + 4);
    bf16x8 bfrag;
    #pragma unroll
    for (int j = 0; j < 8; ++j) {
      x2 = fmaf(xf[j], xf[j], x2);
      const unsigned u = __float_as_uint(xf[j]);
      bfrag[j] = (short)((u + 0x7FFFu + ((u >> 16) & 1u)) >> 16);
    }
    const int kidx = k0 + kg * 8;
    const bf16x8 a0 = *reinterpret_cast<const bf16x8*>(&cenS[(arow +  0) * CSTR + kidx]);
    const bf16x8 a1 = *reinterpret_cast<const bf16x8*>(&cenS[(arow + 16) * CSTR + kidx]);
    const bf16x8 a2 = *reinterpret_cast<const bf16x8*>(&cenS[(arow + 32) * CSTR + kidx]);
    const bf16x8 a3 = *reinterpret_cast<const bf16x8*>(&cenS[(arow + 48) * CSTR + kidx]);
    acc[0] = __builtin_amdgcn_mfma_f32_16x16x32_bf16(a0, bfrag, acc[0], 0, 0, 0);
    acc[1] = __builtin_amdgcn_mfma_f32_16x16x32_bf16(a1, bfrag, acc[1], 0, 0, 0);
    acc[2] = __builtin_amdgcn_mfma_f32_16x16x32_bf16(a2, bfrag, acc[2], 0, 0, 0);
    acc[3] = __builtin_amdgcn_mfma_f32_16x16x32_bf16(a3, bfrag, acc[3], 0, 0, 0);
  }
  x2 += __shfl_xor(x2, 16, 64);
  x2 += __shfl_xor(x2, 32, 64);
  const int col = s0 + (lane & 15);
  #pragma unroll
  for (int t = 0; t < 4; ++t) {
    #pragma unroll
    for (int r = 0; r < 4; ++r) {
      const int cls = t * 16 + (lane >> 4) * 4 + r;
      const float d2 = c2s[cls] + x2 - 2.0f * acc[t][r];
      dist[(size_t)cls * N_SAMP + col] = sqrtf(fmaxf(d2, 1e-12f));
    }
  }
}

// ------------------------------------------------- reduction helpers (1024-thread block)
// slots: v0 sum, v1 sum, v2 min, v3 max, v4 min, v5 max
__device__ __forceinline__ void redSix2(float v0, float v1, float v2, float v3, float v4, float v5,
                                        float* redf, float* bcast) {
  #pragma unroll
  for (int o = 32; o; o >>= 1) {
    v0 += __shfl_xor(v0, o, 64);
    v1 += __shfl_xor(v1, o, 64);
    v2 = fminf(v2, __shfl_xor(v2, o, 64));
    v3 = fmaxf(v3, __shfl_xor(v3, o, 64));
    v4 = fminf(v4, __shfl_xor(v4, o, 64));
    v5 = fmaxf(v5, __shfl_xor(v5, o, 64));
  }
  const int wid = threadIdx.x >> 6;
  if ((threadIdx.x & 63) == 0) {
    redf[wid] = v0; redf[16 + wid] = v1; redf[32 + wid] = v2;
    redf[48 + wid] = v3; redf[64 + wid] = v4; redf[80 + wid] = v5;
  }
  __syncthreads();
  if (threadIdx.x < 16) {
    const int l = threadIdx.x;
    float a0 = redf[l], a1 = redf[16 + l], a2 = redf[32 + l],
          a3 = redf[48 + l], a4 = redf[64 + l], a5 = redf[80 + l];
    #pragma unroll
    for (int o = 8; o; o >>= 1) {
      a0 += __shfl_xor(a0, o, 64);
      a1 += __shfl_xor(a1, o, 64);
      a2 = fminf(a2, __shfl_xor(a2, o, 64));
      a3 = fmaxf(a3, __shfl_xor(a3, o, 64));
      a4 = fminf(a4, __shfl_xor(a4, o, 64));
      a5 = fmaxf(a5, __shfl_xor(a5, o, 64));
    }
    if (l == 0) { bcast[0]=a0; bcast[1]=a1; bcast[2]=a2; bcast[3]=a3; bcast[4]=a4; bcast[5]=a5; }
  }
  __syncthreads();
}

__device__ __forceinline__ int binS(float w, float lo, float sc) {
  int b = (int)((w - lo) * sc);
  b = b < SNBIN - 1 ? b : SNBIN - 1;
  return b > 0 ? b : 0;
}

// scan 4096-bin segment, find boundary bin for K-th smallest; 3 barriers
__device__ __forceinline__ void scanFind(const unsigned* hseg, int K, unsigned* wscan,
                                         int* bsel, unsigned* strict) {
  const int tid = threadIdx.x;
  const int lane = tid & 63, wid = tid >> 6;
  unsigned b4[4]; unsigned s4 = 0;
  #pragma unroll
  for (int j = 0; j < 4; ++j) { b4[j] = hseg[tid * 4 + j]; s4 += b4[j]; }
  unsigned cum = s4;
  #pragma unroll
  for (int d = 1; d < 64; d <<= 1) {
    const unsigned t = (unsigned)__shfl_up((int)cum, d, 64);
    if (lane >= d) cum += t;
  }
  if (lane == 63) wscan[wid] = cum;
  __syncthreads();
  if (tid < 16) {
    unsigned v = wscan[tid];
    #pragma unroll
    for (int d = 1; d < 16; d <<= 1) {
      const unsigned t = (unsigned)__shfl_up((int)v, d, 64);
      if (tid >= d) v += t;
    }
    wscan[tid] = v;
  }
  __syncthreads();
  const unsigned gcum = cum + (wid ? wscan[wid - 1] : 0u);
  const unsigned gprev = gcum - s4;
  if (gcum >= (unsigned)K && gprev < (unsigned)K) {
    unsigned run = gprev;
    #pragma unroll
    for (int j = 0; j < 4; ++j) {
      if (run + b4[j] >= (unsigned)K) { *bsel = tid * 4 + j; *strict = run; break; }
      run += b4[j];
    }
  }
  __syncthreads();
}

// exact wave-level sum of `need` smallest among cnt LDS values (uniform result on all lanes)
__device__ __forceinline__ float wavePeel(const float* buf, int cnt, int need, int lane) {
  float thr = -1e30f, s = 0.f;
  int taken = 0;
  for (int g = 0; g < 64 && taken < need; ++g) {
    float m = 1e30f;
    for (int t = 0; t < 16; ++t) {
      const int idx = lane + t * 64;
      if (idx < cnt) { const float u = buf[idx]; if (u > thr) m = fminf(m, u); }
    }
    #pragma unroll
    for (int o = 32; o; o >>= 1) m = fminf(m, __shfl_xor(m, o, 64));
    int ce = 0;
    for (int t = 0; t < 16; ++t) {
      const int idx = lane + t * 64;
      if (idx < cnt && buf[idx] == m) ++ce;
    }
    #pragma unroll
    for (int o = 32; o; o >>= 1) ce += __shfl_xor(ce, o, 64);
    const int take = (need - taken) < ce ? (need - taken) : ce;
    s += (float)take * m;
    taken += take;
    thr = m;
  }
  return s;
}

// ------------------------------------------------- fused selection (both roles) + loss
__global__ __launch_bounds__(1024, 4) void k_select3(const float* __restrict__ dist,
                                                     const int* __restrict__ y,
                                                     float* __restrict__ means,
                                                     unsigned* __restrict__ done,
                                                     float* __restrict__ out) {
  __shared__ unsigned bitmap[2048];
  __shared__ unsigned hist[2 * SNBIN];
  __shared__ unsigned wscan[16];
  __shared__ float redf[96];
  __shared__ float bcast[8];
  __shared__ float bbufP[1024];
  __shared__ float bbufN[1024];
  __shared__ int cntP, cntN, bselP, bselN;
  __shared__ unsigned strictP, strictN;
  __shared__ float bsumP, bsumN;
  __shared__ int lastflag;

  const int tid = threadIdx.x;
  const int lane = tid & 63;
  const int wid = tid >> 6;
  const int c = blockIdx.x;
  const float* __restrict__ row = dist + (size_t)c * N_SAMP;

  if (tid == 0) {
    cntP = 0; cntN = 0; bselP = 0; bselN = 0;
    strictP = 0u; strictN = 0u; bsumP = 0.f; bsumN = 0.f; lastflag = 0;
  }
  #pragma unroll
  for (int j = 0; j < 2; ++j) {
    unsigned wbits = 0u;
    const int base = tid * 64 + j * 32;
    #pragma unroll
    for (int b = 0; b < 32; ++b) wbits |= (unsigned)(y[base + b] == c) << b;
    bitmap[tid * 2 + j] = wbits;
  }
  __syncthreads();

  // load 64 values/thread (float4) + membership mask; track per-role min/max
  float vals[64];
  unsigned long long mb = 0ull;
  float mnP = 1e30f, mxP = -1e30f, mnN = 1e30f, mxN = -1e30f;
  #pragma unroll
  for (int i = 0; i < 16; ++i) {
    const int base = i * 4096 + tid * 4;
    const float4 v4 = *reinterpret_cast<const float4*>(row + base);
    const unsigned bits = bitmap[base >> 5] >> (base & 31);
    const float vv[4] = {v4.x, v4.y, v4.z, v4.w};
    #pragma unroll
    for (int j = 0; j < 4; ++j) {
      const unsigned bit = (bits >> j) & 1u;
      const float v = vv[j];
      vals[i * 4 + j] = v;
      mb |= (unsigned long long)bit << (i * 4 + j);
      if (bit) { const float w = -v; mnP = fminf(mnP, w); mxP = fmaxf(mxP, w); }
      else     { mnN = fminf(mnN, v); mxN = fmaxf(mxN, v); }
    }
  }
  redSix2(0.f, 0.f, mnP, mxP, mnN, mxN, redf, bcast);
  const float loP = bcast[2], hiP = bcast[3], loN = bcast[4], hiN = bcast[5];
  const bool degP = !(hiP > loP), degN = !(hiN > loN);
  const float scP = degP ? 0.f : (float)SNBIN / (hiP - loP);
  const float scN = degN ? 0.f : (float)SNBIN / (hiN - loN);

  for (int i = tid; i < 2 * SNBIN; i += 1024) hist[i] = 0u;
  __syncthreads();

  #pragma unroll
  for (int i = 0; i < 64; ++i) {
    const float v = vals[i];
    if ((mb >> i) & 1ull) { if (!degP) atomicAdd(&hist[binS(-v, loP, scP)], 1u); }
    else                  { if (!degN) atomicAdd(&hist[SNBIN + binS(v, loN, scN)], 1u); }
  }
  __syncthreads();

  scanFind(&hist[0],     KSEL, wscan, &bselP, &strictP);
  scanFind(&hist[SNBIN], KSEL, wscan, &bselN, &strictN);
  const int BP = bselP, BN = bselN;

  // strict sums + boundary collection
  float ssP = 0.f, ssN = 0.f;
  #pragma unroll
  for (int i = 0; i < 64; ++i) {
    const float v = vals[i];
    if ((mb >> i) & 1ull) {
      if (!degP) {
        const int b = binS(-v, loP, scP);
        if (b < BP) ssP += -v;
        else if (b == BP) { const int p = atomicAdd(&cntP, 1); if (p < 1024) bbufP[p] = -v; }
      }
    } else {
      if (!degN) {
        const int b = binS(v, loN, scN);
        if (b < BN) ssN += v;
        else if (b == BN) { const int p = atomicAdd(&cntN, 1); if (p < 1024) bbufN[p] = v; }
      }
    }
  }
  redSix2(ssP, ssN, 0.f, 0.f, 0.f, 0.f, redf, bcast);
  const float SSP = bcast[0], SSN = bcast[1];
  const int CP = cntP, CN = cntN;
  const int needP = KSEL - (int)strictP, needN = KSEL - (int)strictN;

  // wave-parallel exact boundary resolve (waves 0 & 1 in parallel)
  if (wid == 0 && !degP && CP <= 1024) {
    const float s = wavePeel(bbufP, CP, needP, lane);
    if (lane == 0) bsumP = s;
  }
  if (wid == 1 && !degN && CN <= 1024) {
    const float s = wavePeel(bbufN, CN, needN, lane);
    if (lane == 0) bsumN = s;
  }
  __syncthreads();

  // pathological overflow fallback: exact block-wide peel over registers
  for (int role = 0; role < 2; ++role) {
    const bool deg = role ? degN : degP;
    const int cnt = role ? CN : CP;
    if (deg || cnt <= 1024) continue;
    const int B = role ? BN : BP;
    const int need = role ? needN : needP;
    const float lo = role ? loN : loP, sc = role ? scN : scP;
    float thr = -1e30f, accum = 0.f;
    int taken = 0;
    for (int g = 0; g < 64 && taken < need; ++g) {
      float m = 1e30f;
      #pragma unroll
      for (int i = 0; i < 64; ++i) {
        const int member = (int)((mb >> i) & 1ull);
        if (member == (role ? 0 : 1)) {
          const float w = role ? vals[i] : -vals[i];
          if (binS(w, lo, sc) == B && w > thr) m = fminf(m, w);
        }
      }
      redSix2(0.f, 0.f, m, 0.f, 0.f, 0.f, redf, bcast);
      const float M = bcast[2];
      float ce = 0.f;
      #pragma unroll
      for (int i = 0; i < 64; ++i) {
        const int member = (int)((mb >> i) & 1ull);
        if (member == (role ? 0 : 1)) {
          const float w = role ? vals[i] : -vals[i];
          if (w == M) ce += 1.f;
        }
      }
      redSix2(ce, 0.f, 0.f, 0.f, 0.f, 0.f, redf, bcast);
      const int CE = (int)bcast[0];
      const int take = (need - taken) < CE ? (need - taken) : CE;
      accum += (float)take * M;
      taken += take;
      thr = M;
    }
    if (tid == 0) { if (role) bsumN = accum; else bsumP = accum; }
    __syncthreads();
  }

  const float mP = degP ? (-loP) : -(SSP + bsumP) * (1.0f / 64.0f);
  const float mN = degN ? ( loN) :  (SSN + bsumN) * (1.0f / 64.0f);

  if (tid == 0) {
    __hip_atomic_store(&means[c],      mP, __ATOMIC_RELAXED, __HIP_MEMORY_SCOPE_AGENT);
    __hip_atomic_store(&means[64 + c], mN, __ATOMIC_RELAXED, __HIP_MEMORY_SCOPE_AGENT);
    const unsigned old = __hip_atomic_fetch_add(done, 1u, __ATOMIC_ACQ_REL, __HIP_MEMORY_SCOPE_AGENT);
    lastflag = (old == (unsigned)(NCLS - 1)) ? 1 : 0;
  }
  __syncthreads();
  if (lastflag && tid < 64) {
    const float pm = __hip_atomic_load(&means[tid], __ATOMIC_ACQUIRE, __HIP_MEMORY_SCOPE_AGENT);
    const float nm = __hip_atomic_load(&means[64 + tid], __ATOMIC_ACQUIRE, __HIP_MEMORY_SCOPE_AGENT);
    float pc = fmaxf(1.0f + pm - nm, 0.0f);
    #pragma unroll
    for (int o = 32; o; o >>= 1) pc += __shfl_down(pc, o, 64);
    if (tid == 0) out[0] = pc * (1.0f / 4096.0f);
  }
}

// ----------------------------------------------------------------------
extern "C" void kernel_launch(void* const* d_in, const int* in_sizes, int n_in,
                              void* d_out, int out_size, void* d_ws, size_t ws_size,
                              hipStream_t stream) {
  const float* x = (const float*)d_in[0];
  const int* y = (const int*)d_in[1];
  float* out = (float*)d_out;
  char* w = (char*)d_ws;
  int* counts          = (int*)(w + OFF_COUNTS);
  float* csum          = (float*)(w + OFF_CSUM);
  unsigned short* cenb = (unsigned short*)(w + OFF_CENTERS);
  float* c2            = (float*)(w + OFF_C2);
  float* means         = (float*)(w + OFF_MEANS);
  unsigned* done       = (unsigned*)(w + OFF_DONE);

  const bool big = (ws_size >= (size_t)WS_NEED);
  float* dist = (float*)(w + (big ? OFF_DIST : OFF_DIST_FB));
  unsigned* xb32 = big ? (unsigned*)(w + OFF_XB) : (unsigned*)nullptr;

  hipLaunchKernelGGL(k_init, dim3(64), dim3(256), 0, stream, counts, csum, done);
  hipLaunchKernelGGL(k_class_sums, dim3(1024), dim3(256), 0, stream, x, y, csum, counts, xb32);
  hipLaunchKernelGGL(k_centers, dim3(64), dim3(64), 0, stream, csum, counts, cenb, c2);
  if (big) {
    hipLaunchKernelGGL(k_dist_bf, dim3(N_SAMP / 128), dim3(512), 0, stream,
                       (const unsigned short*)xb32, cenb, c2, dist);
  } else {
    hipLaunchKernelGGL(k_dist_f32, dim3(N_SAMP / 128), dim3(512), 0, stream, x, cenb, c2, dist);
  }
  hipLaunchKernelGGL(k_select3, dim3(NCLS), dim3(1024), 0, stream, dist, y, means, done, out);
}

// Round 7
// 104.039 us; speedup vs baseline: 2.0260x; 2.0260x over previous
//
#include <hip/hip_runtime.h>
#include <math.h>

#define N_SAMP 65536
#define DIM    512
#define NCLS   64
#define KSEL   64
#define SNBIN  4096

// workspace layout (bytes) — main path
#define OFF_COUNTS   0u          // 64 i32
#define OFF_CSUM     256u        // 64*512 f32 -> 131328
#define OFF_CENTERS  131328u     // cenb 64*512 bf16 -> 196864
#define OFF_C2       196864u     // 64 f32 -> 197120
#define OFF_MEANS    197120u     // 128 f32 -> 197632
#define OFF_DONE     197632u     // 1 u32
#define OFF_XB       262144u     // 65536*512 bf16 = 64 MB -> 67371008
#define OFF_DIST     67371008u   // 64*65536 f32 -> 84148224
#define WS_NEED      84148224u
#define OFF_DIST_FB  262144u     // fallback: dist right after header

typedef __attribute__((ext_vector_type(8))) short bf16x8;
typedef __attribute__((ext_vector_type(4))) float f32x4;

__device__ __forceinline__ unsigned short f2bf_rne(float f) {
  const unsigned u = __float_as_uint(f);
  return (unsigned short)((u + 0x7FFFu + ((u >> 16) & 1u)) >> 16);
}

// ---------------------------------------------------------------- init
__global__ __launch_bounds__(256) void k_init(int* __restrict__ counts,
                                              float* __restrict__ csum,
                                              unsigned* __restrict__ done) {
  const int i = blockIdx.x * 256 + threadIdx.x;
  const int stride = gridDim.x * 256;
  if (i < NCLS) counts[i] = 0;
  if (i == 0) *done = 0u;
  for (int j = i; j < NCLS * DIM; j += stride) csum[j] = 0.f;
}

// ------------------------------------------------- class partial sums (+ optional bf16 x emit)
__global__ __launch_bounds__(256) void k_class_sums(const float* __restrict__ x,
                                                    const int* __restrict__ y,
                                                    float* __restrict__ csum,
                                                    int* __restrict__ counts,
                                                    unsigned* __restrict__ xb32) {
  __shared__ int list[4096];
  __shared__ int lcnt;
  const int c  = blockIdx.x >> 4;
  const int r0 = (blockIdx.x & 15) * 4096;
  const int tid = threadIdx.x;
  if (tid == 0) lcnt = 0;
  __syncthreads();
  for (int i = tid; i < 4096; i += 256) {
    if (y[r0 + i] == c) { int p = atomicAdd(&lcnt, 1); list[p] = r0 + i; }
  }
  __syncthreads();
  const int n = lcnt;
  const int dbase = (tid >> 6) * 128 + (tid & 63) * 2;
  const int xoff = dbase >> 1;
  float a0 = 0.f, a1 = 0.f, b0 = 0.f, b1 = 0.f;
  int i = 0;
  for (; i + 2 <= n; i += 2) {
    const int r0i = list[i], r1i = list[i + 1];
    const float* p0 = x + (size_t)r0i * DIM + dbase;
    const float* p1 = x + (size_t)r1i * DIM + dbase;
    const float v00 = p0[0], v01 = p0[1], v10 = p1[0], v11 = p1[1];
    a0 += v00; a1 += v01;
    b0 += v10; b1 += v11;
    if (xb32) {
      xb32[(size_t)r0i * 256 + xoff] = (unsigned)f2bf_rne(v00) | ((unsigned)f2bf_rne(v01) << 16);
      xb32[(size_t)r1i * 256 + xoff] = (unsigned)f2bf_rne(v10) | ((unsigned)f2bf_rne(v11) << 16);
    }
  }
  if (i < n) {
    const int ri = list[i];
    const float* p0 = x + (size_t)ri * DIM + dbase;
    const float v00 = p0[0], v01 = p0[1];
    a0 += v00; a1 += v01;
    if (xb32) xb32[(size_t)ri * 256 + xoff] = (unsigned)f2bf_rne(v00) | ((unsigned)f2bf_rne(v01) << 16);
  }
  a0 += b0; a1 += b1;
  atomicAdd(&csum[c * DIM + dbase], a0);
  atomicAdd(&csum[c * DIM + dbase + 1], a1);
  if (tid == 0) atomicAdd(&counts[c], n);
}

// ------------------------------------------------- finalize centers (bf16) + c2 (f32)
__global__ __launch_bounds__(64) void k_centers(const float* __restrict__ csum,
                                                const int* __restrict__ counts,
                                                unsigned short* __restrict__ cenb,
                                                float* __restrict__ c2) {
  const int c = blockIdx.x, l = threadIdx.x;
  const float inv = 1.0f / (float)counts[c];
  float ss = 0.f;
  #pragma unroll
  for (int j = 0; j < 8; ++j) {
    int d = j * 64 + l;
    float v = csum[c * DIM + d] * inv;
    cenb[c * DIM + d] = f2bf_rne(v);
    ss += v * v;
  }
  #pragma unroll
  for (int o = 32; o; o >>= 1) ss += __shfl_down(ss, o, 64);
  if (l == 0) c2[c] = ss;
}

// ------------------------------------------------- distances via bf16 MFMA, bf16 x input
#define CSTR 520
__global__ __launch_bounds__(512, 4) void k_dist_bf(const unsigned short* __restrict__ xb,
                                                    const unsigned short* __restrict__ cenb,
                                                    const float* __restrict__ c2,
                                                    float* __restrict__ dist) {
  __shared__ unsigned short cenS[NCLS * CSTR];
  __shared__ float c2s[NCLS];

  const int tid = threadIdx.x;
  const int wave = tid >> 6;
  const int lane = tid & 63;
  const int s0 = blockIdx.x * 128 + wave * 16;
  const int samp = s0 + (lane & 15);
  const int kg = lane >> 4;

  for (int q = tid; q < 4096; q += 512) {
    const int row = q >> 6, cc = q & 63;
    const uint4 v = *reinterpret_cast<const uint4*>(cenb + row * DIM + cc * 8);
    *reinterpret_cast<uint4*>(&cenS[row * CSTR + cc * 8]) = v;
  }
  if (tid < NCLS) c2s[tid] = c2[tid];
  __syncthreads();

  f32x4 acc[4] = {f32x4{0,0,0,0}, f32x4{0,0,0,0}, f32x4{0,0,0,0}, f32x4{0,0,0,0}};
  float x2 = 0.f;
  const unsigned short* __restrict__ xrow = xb + (size_t)samp * DIM + kg * 8;
  const int arow = lane & 15;

  #pragma unroll 4
  for (int s = 0; s < 16; ++s) {
    const int k0 = s * 32;
    const bf16x8 bfrag = *reinterpret_cast<const bf16x8*>(xrow + k0);
    const uint4 bu = *reinterpret_cast<const uint4*>(&bfrag);
    {
      const unsigned dw[4] = {bu.x, bu.y, bu.z, bu.w};
      #pragma unroll
      for (int q = 0; q < 4; ++q) {
        const float flo = __uint_as_float(dw[q] << 16);
        const float fhi = __uint_as_float(dw[q] & 0xFFFF0000u);
        x2 = fmaf(flo, flo, x2);
        x2 = fmaf(fhi, fhi, x2);
      }
    }
    const int kidx = k0 + kg * 8;
    const bf16x8 a0 = *reinterpret_cast<const bf16x8*>(&cenS[(arow +  0) * CSTR + kidx]);
    const bf16x8 a1 = *reinterpret_cast<const bf16x8*>(&cenS[(arow + 16) * CSTR + kidx]);
    const bf16x8 a2 = *reinterpret_cast<const bf16x8*>(&cenS[(arow + 32) * CSTR + kidx]);
    const bf16x8 a3 = *reinterpret_cast<const bf16x8*>(&cenS[(arow + 48) * CSTR + kidx]);
    acc[0] = __builtin_amdgcn_mfma_f32_16x16x32_bf16(a0, bfrag, acc[0], 0, 0, 0);
    acc[1] = __builtin_amdgcn_mfma_f32_16x16x32_bf16(a1, bfrag, acc[1], 0, 0, 0);
    acc[2] = __builtin_amdgcn_mfma_f32_16x16x32_bf16(a2, bfrag, acc[2], 0, 0, 0);
    acc[3] = __builtin_amdgcn_mfma_f32_16x16x32_bf16(a3, bfrag, acc[3], 0, 0, 0);
  }

  x2 += __shfl_xor(x2, 16, 64);
  x2 += __shfl_xor(x2, 32, 64);

  const int col = s0 + (lane & 15);
  #pragma unroll
  for (int t = 0; t < 4; ++t) {
    #pragma unroll
    for (int r = 0; r < 4; ++r) {
      const int cls = t * 16 + (lane >> 4) * 4 + r;
      const float d2 = c2s[cls] + x2 - 2.0f * acc[t][r];
      dist[(size_t)cls * N_SAMP + col] = sqrtf(fmaxf(d2, 1e-12f));
    }
  }
}

// ------------------------------------------------- fallback: fp32 x input (proven)
__global__ __launch_bounds__(512, 4) void k_dist_f32(const float* __restrict__ x,
                                                     const unsigned short* __restrict__ cenb,
                                                     const float* __restrict__ c2,
                                                     float* __restrict__ dist) {
  __shared__ unsigned short cenS[NCLS * CSTR];
  __shared__ float c2s[NCLS];
  const int tid = threadIdx.x;
  const int wave = tid >> 6;
  const int lane = tid & 63;
  const int s0 = blockIdx.x * 128 + wave * 16;
  const int samp = s0 + (lane & 15);
  const int kg = lane >> 4;
  for (int q = tid; q < 4096; q += 512) {
    const int row = q >> 6, cc = q & 63;
    const uint4 v = *reinterpret_cast<const uint4*>(cenb + row * DIM + cc * 8);
    *reinterpret_cast<uint4*>(&cenS[row * CSTR + cc * 8]) = v;
  }
  if (tid < NCLS) c2s[tid] = c2[tid];
  __syncthreads();
  f32x4 acc[4] = {f32x4{0,0,0,0}, f32x4{0,0,0,0}, f32x4{0,0,0,0}, f32x4{0,0,0,0}};
  float x2 = 0.f;
  const float* __restrict__ xrow = x + (size_t)samp * DIM + kg * 8;
  const int arow = lane & 15;
  #pragma unroll 4
  for (int s = 0; s < 16; ++s) {
    const int k0 = s * 32;
    float xf[8];
    *reinterpret_cast<float4*>(&xf[0]) = *reinterpret_cast<const float4*>(xrow + k0);
    *reinterpret_cast<float4*>(&xf[4]) = *reinterpret_cast<const float4*>(xrow + k0 + 4);
    bf16x8 bfrag;
    #pragma unroll
    for (int j = 0; j < 8; ++j) {
      x2 = fmaf(xf[j], xf[j], x2);
      const unsigned u = __float_as_uint(xf[j]);
      bfrag[j] = (short)((u + 0x7FFFu + ((u >> 16) & 1u)) >> 16);
    }
    const int kidx = k0 + kg * 8;
    const bf16x8 a0 = *reinterpret_cast<const bf16x8*>(&cenS[(arow +  0) * CSTR + kidx]);
    const bf16x8 a1 = *reinterpret_cast<const bf16x8*>(&cenS[(arow + 16) * CSTR + kidx]);
    const bf16x8 a2 = *reinterpret_cast<const bf16x8*>(&cenS[(arow + 32) * CSTR + kidx]);
    const bf16x8 a3 = *reinterpret_cast<const bf16x8*>(&cenS[(arow + 48) * CSTR + kidx]);
    acc[0] = __builtin_amdgcn_mfma_f32_16x16x32_bf16(a0, bfrag, acc[0], 0, 0, 0);
    acc[1] = __builtin_amdgcn_mfma_f32_16x16x32_bf16(a1, bfrag, acc[1], 0, 0, 0);
    acc[2] = __builtin_amdgcn_mfma_f32_16x16x32_bf16(a2, bfrag, acc[2], 0, 0, 0);
    acc[3] = __builtin_amdgcn_mfma_f32_16x16x32_bf16(a3, bfrag, acc[3], 0, 0, 0);
  }
  x2 += __shfl_xor(x2, 16, 64);
  x2 += __shfl_xor(x2, 32, 64);
  const int col = s0 + (lane & 15);
  #pragma unroll
  for (int t = 0; t < 4; ++t) {
    #pragma unroll
    for (int r = 0; r < 4; ++r) {
      const int cls = t * 16 + (lane >> 4) * 4 + r;
      const float d2 = c2s[cls] + x2 - 2.0f * acc[t][r];
      dist[(size_t)cls * N_SAMP + col] = sqrtf(fmaxf(d2, 1e-12f));
    }
  }
}

// ------------------------------------------------- reduction helper (1024-thread block)
// slots: v0 sum, v2 min, v3 max
__device__ __forceinline__ void redB(float v0, float v2, float v3, float* redf, float* bcast) {
  #pragma unroll
  for (int o = 32; o; o >>= 1) {
    v0 += __shfl_xor(v0, o, 64);
    v2 = fminf(v2, __shfl_xor(v2, o, 64));
    v3 = fmaxf(v3, __shfl_xor(v3, o, 64));
  }
  const int wid = threadIdx.x >> 6;
  if ((threadIdx.x & 63) == 0) { redf[wid] = v0; redf[16 + wid] = v2; redf[32 + wid] = v3; }
  __syncthreads();
  if (threadIdx.x < 16) {
    const int l = threadIdx.x;
    float a0 = redf[l], a2 = redf[16 + l], a3 = redf[32 + l];
    #pragma unroll
    for (int o = 8; o; o >>= 1) {
      a0 += __shfl_xor(a0, o, 64);
      a2 = fminf(a2, __shfl_xor(a2, o, 64));
      a3 = fmaxf(a3, __shfl_xor(a3, o, 64));
    }
    if (l == 0) { bcast[0] = a0; bcast[2] = a2; bcast[3] = a3; }
  }
  __syncthreads();
}

__device__ __forceinline__ int binS(float w, float lo, float sc) {
  int b = (int)((w - lo) * sc);
  b = b < SNBIN - 1 ? b : SNBIN - 1;
  return b > 0 ? b : 0;
}

// exact wave-level sum of `need` smallest among cnt LDS values
__device__ __forceinline__ float wavePeel(const float* buf, int cnt, int need, int lane) {
  float thr = -1e30f, s = 0.f;
  int taken = 0;
  for (int g = 0; g < 64 && taken < need; ++g) {
    float m = 1e30f;
    for (int t = 0; t < 16; ++t) {
      const int idx = lane + t * 64;
      if (idx < cnt) { const float u = buf[idx]; if (u > thr) m = fminf(m, u); }
    }
    #pragma unroll
    for (int o = 32; o; o >>= 1) m = fminf(m, __shfl_xor(m, o, 64));
    int ce = 0;
    for (int t = 0; t < 16; ++t) {
      const int idx = lane + t * 64;
      if (idx < cnt && buf[idx] == m) ++ce;
    }
    #pragma unroll
    for (int o = 32; o; o >>= 1) ce += __shfl_xor(ce, o, 64);
    const int take = (need - taken) < ce ? (need - taken) : ce;
    s += (float)take * m;
    taken += take;
    thr = m;
  }
  return s;
}

// ------------------------------------------------- stateless selection (no register cache) + fused loss
// grid 128: c = bx>>1, role = bx&1 (0: largest dists among members; 1: smallest among non-members)
__global__ __launch_bounds__(1024, 2) void k_select4(const float* __restrict__ dist,
                                                     const int* __restrict__ y,
                                                     float* __restrict__ means,
                                                     unsigned* __restrict__ done,
                                                     float* __restrict__ out) {
  __shared__ unsigned bitmap[2048];
  __shared__ unsigned hist[SNBIN];
  __shared__ unsigned wscan[16];
  __shared__ float redf[48];
  __shared__ float bcast[4];
  __shared__ float bbuf[1024];
  __shared__ int bcnt_s, bsel_s;
  __shared__ unsigned strict_s;
  __shared__ float bsum_s;
  __shared__ int lastflag;

  const int tid = threadIdx.x;
  const int lane = tid & 63;
  const int wid = tid >> 6;
  const int c = blockIdx.x >> 1;
  const int role = blockIdx.x & 1;
  const float* __restrict__ row = dist + (size_t)c * N_SAMP;

  if (tid == 0) { bcnt_s = 0; bsel_s = 0; strict_s = 0u; bsum_s = 0.f; lastflag = 0; }

  // membership bitmap via int4 loads (64 y per thread)
  {
    const int4* __restrict__ y4 = (const int4*)(y + tid * 64);
    unsigned w0 = 0u, w1 = 0u;
    #pragma unroll
    for (int i = 0; i < 8; ++i) {
      const int4 a = y4[i];
      w0 |= (unsigned)(a.x == c) << (i * 4);
      w0 |= (unsigned)(a.y == c) << (i * 4 + 1);
      w0 |= (unsigned)(a.z == c) << (i * 4 + 2);
      w0 |= (unsigned)(a.w == c) << (i * 4 + 3);
    }
    #pragma unroll
    for (int i = 0; i < 8; ++i) {
      const int4 a = y4[8 + i];
      w1 |= (unsigned)(a.x == c) << (i * 4);
      w1 |= (unsigned)(a.y == c) << (i * 4 + 1);
      w1 |= (unsigned)(a.z == c) << (i * 4 + 2);
      w1 |= (unsigned)(a.w == c) << (i * 4 + 3);
    }
    bitmap[tid * 2] = w0;
    bitmap[tid * 2 + 1] = w1;
  }
  __syncthreads();

  // pass A: masked min/max (w = role? v : -v; include if bit != role)
  float mn = 1e30f, mx = -1e30f;
  #pragma unroll 4
  for (int i = 0; i < 16; ++i) {
    const int base = i * 4096 + tid * 4;
    const float4 v4 = *reinterpret_cast<const float4*>(row + base);
    const unsigned bits = bitmap[base >> 5] >> (base & 31);
    const float vv[4] = {v4.x, v4.y, v4.z, v4.w};
    #pragma unroll
    for (int j = 0; j < 4; ++j) {
      if ((int)((bits >> j) & 1u) != role) {
        const float w = role ? vv[j] : -vv[j];
        mn = fminf(mn, w);
        mx = fmaxf(mx, w);
      }
    }
  }
  redB(0.f, mn, mx, redf, bcast);
  const float lo = bcast[2], hi = bcast[3];
  const bool deg = !(hi > lo);
  float meanval;

  if (deg) {
    meanval = role ? lo : -lo;
  } else {
    const float sc = (float)SNBIN / (hi - lo);
    for (int i = tid; i < SNBIN; i += 1024) hist[i] = 0u;
    __syncthreads();

    // pass B: histogram
    #pragma unroll 4
    for (int i = 0; i < 16; ++i) {
      const int base = i * 4096 + tid * 4;
      const float4 v4 = *reinterpret_cast<const float4*>(row + base);
      const unsigned bits = bitmap[base >> 5] >> (base & 31);
      const float vv[4] = {v4.x, v4.y, v4.z, v4.w};
      #pragma unroll
      for (int j = 0; j < 4; ++j) {
        if ((int)((bits >> j) & 1u) != role) {
          const float w = role ? vv[j] : -vv[j];
          atomicAdd(&hist[binS(w, lo, sc)], 1u);
        }
      }
    }
    __syncthreads();

    // scan 4096 bins (4/thread), find boundary bin
    {
      unsigned b4[4]; unsigned s4 = 0;
      #pragma unroll
      for (int j = 0; j < 4; ++j) { b4[j] = hist[tid * 4 + j]; s4 += b4[j]; }
      unsigned cum = s4;
      #pragma unroll
      for (int d = 1; d < 64; d <<= 1) {
        const unsigned t = (unsigned)__shfl_up((int)cum, d, 64);
        if (lane >= d) cum += t;
      }
      if (lane == 63) wscan[wid] = cum;
      __syncthreads();
      if (tid < 16) {
        unsigned v = wscan[tid];
        #pragma unroll
        for (int d = 1; d < 16; d <<= 1) {
          const unsigned t = (unsigned)__shfl_up((int)v, d, 64);
          if (tid >= d) v += t;
        }
        wscan[tid] = v;
      }
      __syncthreads();
      const unsigned gcum = cum + (wid ? wscan[wid - 1] : 0u);
      const unsigned gprev = gcum - s4;
      if (gcum >= (unsigned)KSEL && gprev < (unsigned)KSEL) {
        unsigned run = gprev;
        #pragma unroll
        for (int j = 0; j < 4; ++j) {
          if (run + b4[j] >= (unsigned)KSEL) { bsel_s = tid * 4 + j; strict_s = run; break; }
          run += b4[j];
        }
      }
      __syncthreads();
    }
    const int B = bsel_s;
    const int need = KSEL - (int)strict_s;

    // pass C: strict sum + boundary collect
    float ss = 0.f;
    #pragma unroll 4
    for (int i = 0; i < 16; ++i) {
      const int base = i * 4096 + tid * 4;
      const float4 v4 = *reinterpret_cast<const float4*>(row + base);
      const unsigned bits = bitmap[base >> 5] >> (base & 31);
      const float vv[4] = {v4.x, v4.y, v4.z, v4.w};
      #pragma unroll
      for (int j = 0; j < 4; ++j) {
        if ((int)((bits >> j) & 1u) != role) {
          const float w = role ? vv[j] : -vv[j];
          const int b = binS(w, lo, sc);
          if (b < B) ss += w;
          else if (b == B) { const int p = atomicAdd(&bcnt_s, 1); if (p < 1024) bbuf[p] = w; }
        }
      }
    }
    redB(ss, 0.f, 0.f, redf, bcast);
    const float SS = bcast[0];
    const int cnt = bcnt_s;

    if (cnt <= 1024) {
      if (wid == 0) {
        const float s = wavePeel(bbuf, cnt, need, lane);
        if (lane == 0) bsum_s = s;
      }
      __syncthreads();
    } else {
      // pathological overflow: exact block-wide peel via global re-reads (unreachable in practice)
      float thr = -1e30f, accum = 0.f;
      int taken = 0;
      for (int g = 0; g < 64 && taken < need; ++g) {
        float m = 1e30f;
        for (int i = 0; i < 16; ++i) {
          const int base = i * 4096 + tid * 4;
          const float4 v4 = *reinterpret_cast<const float4*>(row + base);
          const unsigned bits = bitmap[base >> 5] >> (base & 31);
          const float vv[4] = {v4.x, v4.y, v4.z, v4.w};
          for (int j = 0; j < 4; ++j) {
            if ((int)((bits >> j) & 1u) != role) {
              const float w = role ? vv[j] : -vv[j];
              if (binS(w, lo, sc) == B && w > thr) m = fminf(m, w);
            }
          }
        }
        redB(0.f, m, 0.f, redf, bcast);
        const float M = bcast[2];
        float ce = 0.f;
        for (int i = 0; i < 16; ++i) {
          const int base = i * 4096 + tid * 4;
          const float4 v4 = *reinterpret_cast<const float4*>(row + base);
          const unsigned bits = bitmap[base >> 5] >> (base & 31);
          const float vv[4] = {v4.x, v4.y, v4.z, v4.w};
          for (int j = 0; j < 4; ++j) {
            if ((int)((bits >> j) & 1u) != role) {
              const float w = role ? vv[j] : -vv[j];
              if (w == M) ce += 1.f;
            }
          }
        }
        redB(ce, 0.f, 0.f, redf, bcast);
        const int CE = (int)bcast[0];
        const int take = (need - taken) < CE ? (need - taken) : CE;
        accum += (float)take * M;
        taken += take;
        thr = M;
      }
      if (tid == 0) bsum_s = accum;
      __syncthreads();
    }

    const float total = SS + bsum_s;
    meanval = role ? total * (1.0f / 64.0f) : -total * (1.0f / 64.0f);
  }

  // publish mean; last block computes loss
  if (tid == 0) {
    __hip_atomic_store(&means[role * 64 + c], meanval, __ATOMIC_RELAXED, __HIP_MEMORY_SCOPE_AGENT);
    const unsigned old = __hip_atomic_fetch_add(done, 1u, __ATOMIC_ACQ_REL, __HIP_MEMORY_SCOPE_AGENT);
    lastflag = (old == 127u) ? 1 : 0;
  }
  __syncthreads();
  if (lastflag && tid < 64) {
    const float pm = __hip_atomic_load(&means[tid], __ATOMIC_ACQUIRE, __HIP_MEMORY_SCOPE_AGENT);
    const float nm = __hip_atomic_load(&means[64 + tid], __ATOMIC_ACQUIRE, __HIP_MEMORY_SCOPE_AGENT);
    float pc = fmaxf(1.0f + pm - nm, 0.0f);
    #pragma unroll
    for (int o = 32; o; o >>= 1) pc += __shfl_down(pc, o, 64);
    if (tid == 0) out[0] = pc * (1.0f / 4096.0f);
  }
}

// ----------------------------------------------------------------------
extern "C" void kernel_launch(void* const* d_in, const int* in_sizes, int n_in,
                              void* d_out, int out_size, void* d_ws, size_t ws_size,
                              hipStream_t stream) {
  const float* x = (const float*)d_in[0];
  const int* y = (const int*)d_in[1];
  float* out = (float*)d_out;
  char* w = (char*)d_ws;
  int* counts          = (int*)(w + OFF_COUNTS);
  float* csum          = (float*)(w + OFF_CSUM);
  unsigned short* cenb = (unsigned short*)(w + OFF_CENTERS);
  float* c2            = (float*)(w + OFF_C2);
  float* means         = (float*)(w + OFF_MEANS);
  unsigned* done       = (unsigned*)(w + OFF_DONE);

  const bool big = (ws_size >= (size_t)WS_NEED);
  float* dist = (float*)(w + (big ? OFF_DIST : OFF_DIST_FB));
  unsigned* xb32 = big ? (unsigned*)(w + OFF_XB) : (unsigned*)nullptr;

  hipLaunchKernelGGL(k_init, dim3(64), dim3(256), 0, stream, counts, csum, done);
  hipLaunchKernelGGL(k_class_sums, dim3(1024), dim3(256), 0, stream, x, y, csum, counts, xb32);
  hipLaunchKernelGGL(k_centers, dim3(64), dim3(64), 0, stream, csum, counts, cenb, c2);
  if (big) {
    hipLaunchKernelGGL(k_dist_bf, dim3(N_SAMP / 128), dim3(512), 0, stream,
                       (const unsigned short*)xb32, cenb, c2, dist);
  } else {
    hipLaunchKernelGGL(k_dist_f32, dim3(N_SAMP / 128), dim3(512), 0, stream, x, cenb, c2, dist);
  }
  hipLaunchKernelGGL(k_select4, dim3(128), dim3(1024), 0, stream, dist, y, means, done, out);
}

// Round 8
// 102.486 us; speedup vs baseline: 2.0566x; 1.0152x over previous
//
#include <hip/hip_runtime.h>
#include <math.h>

#define N_SAMP 65536
#define DIM    512
#define NCLS   64
#define KSEL   64
#define SNBIN  4096

// workspace layout (bytes) — main path
#define OFF_COUNTS   0u          // 64 i32
#define OFF_CSUM     256u        // 64*512 f32 -> 131328
#define OFF_CENTERS  131328u     // cenb 64*512 bf16 -> 196864
#define OFF_C2       196864u     // 64 f32 -> 197120
#define OFF_MEANS    197120u     // 128 f32 -> 197632
#define OFF_DONE     197632u     // 1 u32
#define OFF_XB       262144u     // 65536*512 bf16 = 64 MB -> 67371008
#define OFF_DIST     67371008u   // 64*65536 f32 -> 84148224
#define WS_NEED      84148224u
#define OFF_DIST_FB  262144u     // fallback: dist right after header

typedef __attribute__((ext_vector_type(8))) short bf16x8;
typedef __attribute__((ext_vector_type(4))) float f32x4;

__device__ __forceinline__ unsigned short f2bf_rne(float f) {
  const unsigned u = __float_as_uint(f);
  return (unsigned short)((u + 0x7FFFu + ((u >> 16) & 1u)) >> 16);
}

// ---------------------------------------------------------------- init
__global__ __launch_bounds__(256) void k_init(int* __restrict__ counts,
                                              float* __restrict__ csum,
                                              unsigned* __restrict__ done) {
  const int i = blockIdx.x * 256 + threadIdx.x;
  const int stride = gridDim.x * 256;
  if (i < NCLS) counts[i] = 0;
  if (i == 0) *done = 0u;
  for (int j = i; j < NCLS * DIM; j += stride) csum[j] = 0.f;
}

// ------------------------------------------------- class partial sums (+ bf16 x emit), 8-row ILP
__global__ __launch_bounds__(256) void k_class_sums(const float* __restrict__ x,
                                                    const int* __restrict__ y,
                                                    float* __restrict__ csum,
                                                    int* __restrict__ counts,
                                                    unsigned* __restrict__ xb32) {
  __shared__ int list[4096];
  __shared__ int lcnt;
  const int c  = blockIdx.x >> 4;
  const int r0 = (blockIdx.x & 15) * 4096;
  const int tid = threadIdx.x;
  if (tid == 0) lcnt = 0;
  __syncthreads();
  for (int i = tid; i < 4096; i += 256) {
    if (y[r0 + i] == c) { int p = atomicAdd(&lcnt, 1); list[p] = r0 + i; }
  }
  __syncthreads();
  const int n = lcnt;
  const int dbase = (tid >> 6) * 128 + (tid & 63) * 2;
  const int xoff = dbase >> 1;
  float a0 = 0.f, a1 = 0.f;
  int i = 0;
  // 8-row unrolled main loop: 8 independent loads in flight per lane
  for (; i + 8 <= n; i += 8) {
    int r[8];
    #pragma unroll
    for (int q = 0; q < 8; ++q) r[q] = list[i + q];
    float2 v[8];
    #pragma unroll
    for (int q = 0; q < 8; ++q)
      v[q] = *reinterpret_cast<const float2*>(x + (size_t)r[q] * DIM + dbase);
    #pragma unroll
    for (int q = 0; q < 8; ++q) { a0 += v[q].x; a1 += v[q].y; }
    if (xb32) {
      #pragma unroll
      for (int q = 0; q < 8; ++q)
        xb32[(size_t)r[q] * 256 + xoff] =
            (unsigned)f2bf_rne(v[q].x) | ((unsigned)f2bf_rne(v[q].y) << 16);
    }
  }
  for (; i + 2 <= n; i += 2) {
    const int r0i = list[i], r1i = list[i + 1];
    const float2 v0 = *reinterpret_cast<const float2*>(x + (size_t)r0i * DIM + dbase);
    const float2 v1 = *reinterpret_cast<const float2*>(x + (size_t)r1i * DIM + dbase);
    a0 += v0.x + v1.x; a1 += v0.y + v1.y;
    if (xb32) {
      xb32[(size_t)r0i * 256 + xoff] = (unsigned)f2bf_rne(v0.x) | ((unsigned)f2bf_rne(v0.y) << 16);
      xb32[(size_t)r1i * 256 + xoff] = (unsigned)f2bf_rne(v1.x) | ((unsigned)f2bf_rne(v1.y) << 16);
    }
  }
  if (i < n) {
    const int ri = list[i];
    const float2 v0 = *reinterpret_cast<const float2*>(x + (size_t)ri * DIM + dbase);
    a0 += v0.x; a1 += v0.y;
    if (xb32) xb32[(size_t)ri * 256 + xoff] = (unsigned)f2bf_rne(v0.x) | ((unsigned)f2bf_rne(v0.y) << 16);
  }
  atomicAdd(&csum[c * DIM + dbase], a0);
  atomicAdd(&csum[c * DIM + dbase + 1], a1);
  if (tid == 0) atomicAdd(&counts[c], n);
}

// ------------------------------------------------- finalize centers (bf16) + c2 (f32)
__global__ __launch_bounds__(64) void k_centers(const float* __restrict__ csum,
                                                const int* __restrict__ counts,
                                                unsigned short* __restrict__ cenb,
                                                float* __restrict__ c2) {
  const int c = blockIdx.x, l = threadIdx.x;
  const float inv = 1.0f / (float)counts[c];
  float ss = 0.f;
  #pragma unroll
  for (int j = 0; j < 8; ++j) {
    int d = j * 64 + l;
    float v = csum[c * DIM + d] * inv;
    cenb[c * DIM + d] = f2bf_rne(v);
    ss += v * v;
  }
  #pragma unroll
  for (int o = 32; o; o >>= 1) ss += __shfl_down(ss, o, 64);
  if (l == 0) c2[c] = ss;
}

// ------------------------------------------------- distances via bf16 MFMA, bf16 x input
#define CSTR 520
__global__ __launch_bounds__(512, 4) void k_dist_bf(const unsigned short* __restrict__ xb,
                                                    const unsigned short* __restrict__ cenb,
                                                    const float* __restrict__ c2,
                                                    float* __restrict__ dist) {
  __shared__ unsigned short cenS[NCLS * CSTR];
  __shared__ float c2s[NCLS];

  const int tid = threadIdx.x;
  const int wave = tid >> 6;
  const int lane = tid & 63;
  const int s0 = blockIdx.x * 128 + wave * 16;
  const int samp = s0 + (lane & 15);
  const int kg = lane >> 4;

  for (int q = tid; q < 4096; q += 512) {
    const int row = q >> 6, cc = q & 63;
    const uint4 v = *reinterpret_cast<const uint4*>(cenb + row * DIM + cc * 8);
    *reinterpret_cast<uint4*>(&cenS[row * CSTR + cc * 8]) = v;
  }
  if (tid < NCLS) c2s[tid] = c2[tid];
  __syncthreads();

  f32x4 acc[4] = {f32x4{0,0,0,0}, f32x4{0,0,0,0}, f32x4{0,0,0,0}, f32x4{0,0,0,0}};
  float x2 = 0.f;
  const unsigned short* __restrict__ xrow = xb + (size_t)samp * DIM + kg * 8;
  const int arow = lane & 15;

  #pragma unroll 4
  for (int s = 0; s < 16; ++s) {
    const int k0 = s * 32;
    const bf16x8 bfrag = *reinterpret_cast<const bf16x8*>(xrow + k0);
    const uint4 bu = *reinterpret_cast<const uint4*>(&bfrag);
    {
      const unsigned dw[4] = {bu.x, bu.y, bu.z, bu.w};
      #pragma unroll
      for (int q = 0; q < 4; ++q) {
        const float flo = __uint_as_float(dw[q] << 16);
        const float fhi = __uint_as_float(dw[q] & 0xFFFF0000u);
        x2 = fmaf(flo, flo, x2);
        x2 = fmaf(fhi, fhi, x2);
      }
    }
    const int kidx = k0 + kg * 8;
    const bf16x8 a0 = *reinterpret_cast<const bf16x8*>(&cenS[(arow +  0) * CSTR + kidx]);
    const bf16x8 a1 = *reinterpret_cast<const bf16x8*>(&cenS[(arow + 16) * CSTR + kidx]);
    const bf16x8 a2 = *reinterpret_cast<const bf16x8*>(&cenS[(arow + 32) * CSTR + kidx]);
    const bf16x8 a3 = *reinterpret_cast<const bf16x8*>(&cenS[(arow + 48) * CSTR + kidx]);
    acc[0] = __builtin_amdgcn_mfma_f32_16x16x32_bf16(a0, bfrag, acc[0], 0, 0, 0);
    acc[1] = __builtin_amdgcn_mfma_f32_16x16x32_bf16(a1, bfrag, acc[1], 0, 0, 0);
    acc[2] = __builtin_amdgcn_mfma_f32_16x16x32_bf16(a2, bfrag, acc[2], 0, 0, 0);
    acc[3] = __builtin_amdgcn_mfma_f32_16x16x32_bf16(a3, bfrag, acc[3], 0, 0, 0);
  }

  x2 += __shfl_xor(x2, 16, 64);
  x2 += __shfl_xor(x2, 32, 64);

  const int col = s0 + (lane & 15);
  #pragma unroll
  for (int t = 0; t < 4; ++t) {
    #pragma unroll
    for (int r = 0; r < 4; ++r) {
      const int cls = t * 16 + (lane >> 4) * 4 + r;
      const float d2 = c2s[cls] + x2 - 2.0f * acc[t][r];
      dist[(size_t)cls * N_SAMP + col] = sqrtf(fmaxf(d2, 1e-12f));
    }
  }
}

// ------------------------------------------------- fallback: fp32 x input (proven)
__global__ __launch_bounds__(512, 4) void k_dist_f32(const float* __restrict__ x,
                                                     const unsigned short* __restrict__ cenb,
                                                     const float* __restrict__ c2,
                                                     float* __restrict__ dist) {
  __shared__ unsigned short cenS[NCLS * CSTR];
  __shared__ float c2s[NCLS];
  const int tid = threadIdx.x;
  const int wave = tid >> 6;
  const int lane = tid & 63;
  const int s0 = blockIdx.x * 128 + wave * 16;
  const int samp = s0 + (lane & 15);
  const int kg = lane >> 4;
  for (int q = tid; q < 4096; q += 512) {
    const int row = q >> 6, cc = q & 63;
    const uint4 v = *reinterpret_cast<const uint4*>(cenb + row * DIM + cc * 8);
    *reinterpret_cast<uint4*>(&cenS[row * CSTR + cc * 8]) = v;
  }
  if (tid < NCLS) c2s[tid] = c2[tid];
  __syncthreads();
  f32x4 acc[4] = {f32x4{0,0,0,0}, f32x4{0,0,0,0}, f32x4{0,0,0,0}, f32x4{0,0,0,0}};
  float x2 = 0.f;
  const float* __restrict__ xrow = x + (size_t)samp * DIM + kg * 8;
  const int arow = lane & 15;
  #pragma unroll 4
  for (int s = 0; s < 16; ++s) {
    const int k0 = s * 32;
    float xf[8];
    *reinterpret_cast<float4*>(&xf[0]) = *reinterpret_cast<const float4*>(xrow + k0);
    *reinterpret_cast<float4*>(&xf[4]) = *reinterpret_cast<const float4*>(xrow + k0 + 4);
    bf16x8 bfrag;
    #pragma unroll
    for (int j = 0; j < 8; ++j) {
      x2 = fmaf(xf[j], xf[j], x2);
      const unsigned u = __float_as_uint(xf[j]);
      bfrag[j] = (short)((u + 0x7FFFu + ((u >> 16) & 1u)) >> 16);
    }
    const int kidx = k0 + kg * 8;
    const bf16x8 a0 = *reinterpret_cast<const bf16x8*>(&cenS[(arow +  0) * CSTR + kidx]);
    const bf16x8 a1 = *reinterpret_cast<const bf16x8*>(&cenS[(arow + 16) * CSTR + kidx]);
    const bf16x8 a2 = *reinterpret_cast<const bf16x8*>(&cenS[(arow + 32) * CSTR + kidx]);
    const bf16x8 a3 = *reinterpret_cast<const bf16x8*>(&cenS[(arow + 48) * CSTR + kidx]);
    acc[0] = __builtin_amdgcn_mfma_f32_16x16x32_bf16(a0, bfrag, acc[0], 0, 0, 0);
    acc[1] = __builtin_amdgcn_mfma_f32_16x16x32_bf16(a1, bfrag, acc[1], 0, 0, 0);
    acc[2] = __builtin_amdgcn_mfma_f32_16x16x32_bf16(a2, bfrag, acc[2], 0, 0, 0);
    acc[3] = __builtin_amdgcn_mfma_f32_16x16x32_bf16(a3, bfrag, acc[3], 0, 0, 0);
  }
  x2 += __shfl_xor(x2, 16, 64);
  x2 += __shfl_xor(x2, 32, 64);
  const int col = s0 + (lane & 15);
  #pragma unroll
  for (int t = 0; t < 4; ++t) {
    #pragma unroll
    for (int r = 0; r < 4; ++r) {
      const int cls = t * 16 + (lane >> 4) * 4 + r;
      const float d2 = c2s[cls] + x2 - 2.0f * acc[t][r];
      dist[(size_t)cls * N_SAMP + col] = sqrtf(fmaxf(d2, 1e-12f));
    }
  }
}

// ------------------------------------------------- reduction helper (1024-thread block)
__device__ __forceinline__ void redB(float v0, float v2, float v3, float* redf, float* bcast) {
  #pragma unroll
  for (int o = 32; o; o >>= 1) {
    v0 += __shfl_xor(v0, o, 64);
    v2 = fminf(v2, __shfl_xor(v2, o, 64));
    v3 = fmaxf(v3, __shfl_xor(v3, o, 64));
  }
  const int wid = threadIdx.x >> 6;
  if ((threadIdx.x & 63) == 0) { redf[wid] = v0; redf[16 + wid] = v2; redf[32 + wid] = v3; }
  __syncthreads();
  if (threadIdx.x < 16) {
    const int l = threadIdx.x;
    float a0 = redf[l], a2 = redf[16 + l], a3 = redf[32 + l];
    #pragma unroll
    for (int o = 8; o; o >>= 1) {
      a0 += __shfl_xor(a0, o, 64);
      a2 = fminf(a2, __shfl_xor(a2, o, 64));
      a3 = fmaxf(a3, __shfl_xor(a3, o, 64));
    }
    if (l == 0) { bcast[0] = a0; bcast[2] = a2; bcast[3] = a3; }
  }
  __syncthreads();
}

__device__ __forceinline__ int binS(float w, float lo, float sc) {
  int b = (int)((w - lo) * sc);
  b = b < SNBIN - 1 ? b : SNBIN - 1;
  return b > 0 ? b : 0;
}

// exact wave-level sum of `need` smallest among cnt LDS values
__device__ __forceinline__ float wavePeel(const float* buf, int cnt, int need, int lane) {
  float thr = -1e30f, s = 0.f;
  int taken = 0;
  for (int g = 0; g < 64 && taken < need; ++g) {
    float m = 1e30f;
    for (int t = 0; t < 16; ++t) {
      const int idx = lane + t * 64;
      if (idx < cnt) { const float u = buf[idx]; if (u > thr) m = fminf(m, u); }
    }
    #pragma unroll
    for (int o = 32; o; o >>= 1) m = fminf(m, __shfl_xor(m, o, 64));
    int ce = 0;
    for (int t = 0; t < 16; ++t) {
      const int idx = lane + t * 64;
      if (idx < cnt && buf[idx] == m) ++ce;
    }
    #pragma unroll
    for (int o = 32; o; o >>= 1) ce += __shfl_xor(ce, o, 64);
    const int take = (need - taken) < ce ? (need - taken) : ce;
    s += (float)take * m;
    taken += take;
    thr = m;
  }
  return s;
}

// ------------------------------------------------- stateless selection + fused loss
// grid 128: c = bx>>1, role = bx&1
__global__ __launch_bounds__(1024, 2) void k_select4(const float* __restrict__ dist,
                                                     const int* __restrict__ y,
                                                     float* __restrict__ means,
                                                     unsigned* __restrict__ done,
                                                     float* __restrict__ out) {
  __shared__ unsigned bitmap[2048];
  __shared__ unsigned hist[SNBIN];
  __shared__ unsigned wscan[16];
  __shared__ float redf[48];
  __shared__ float bcast[4];
  __shared__ float bbuf[1024];
  __shared__ int bcnt_s, bsel_s;
  __shared__ unsigned strict_s;
  __shared__ float bsum_s;
  __shared__ int lastflag;

  const int tid = threadIdx.x;
  const int lane = tid & 63;
  const int wid = tid >> 6;
  const int c = blockIdx.x >> 1;
  const int role = blockIdx.x & 1;
  const float* __restrict__ row = dist + (size_t)c * N_SAMP;

  if (tid == 0) { bcnt_s = 0; bsel_s = 0; strict_s = 0u; bsum_s = 0.f; lastflag = 0; }

  {
    const int4* __restrict__ y4 = (const int4*)(y + tid * 64);
    unsigned w0 = 0u, w1 = 0u;
    #pragma unroll
    for (int i = 0; i < 8; ++i) {
      const int4 a = y4[i];
      w0 |= (unsigned)(a.x == c) << (i * 4);
      w0 |= (unsigned)(a.y == c) << (i * 4 + 1);
      w0 |= (unsigned)(a.z == c) << (i * 4 + 2);
      w0 |= (unsigned)(a.w == c) << (i * 4 + 3);
    }
    #pragma unroll
    for (int i = 0; i < 8; ++i) {
      const int4 a = y4[8 + i];
      w1 |= (unsigned)(a.x == c) << (i * 4);
      w1 |= (unsigned)(a.y == c) << (i * 4 + 1);
      w1 |= (unsigned)(a.z == c) << (i * 4 + 2);
      w1 |= (unsigned)(a.w == c) << (i * 4 + 3);
    }
    bitmap[tid * 2] = w0;
    bitmap[tid * 2 + 1] = w1;
  }
  __syncthreads();

  float mn = 1e30f, mx = -1e30f;
  #pragma unroll 4
  for (int i = 0; i < 16; ++i) {
    const int base = i * 4096 + tid * 4;
    const float4 v4 = *reinterpret_cast<const float4*>(row + base);
    const unsigned bits = bitmap[base >> 5] >> (base & 31);
    const float vv[4] = {v4.x, v4.y, v4.z, v4.w};
    #pragma unroll
    for (int j = 0; j < 4; ++j) {
      if ((int)((bits >> j) & 1u) != role) {
        const float w = role ? vv[j] : -vv[j];
        mn = fminf(mn, w);
        mx = fmaxf(mx, w);
      }
    }
  }
  redB(0.f, mn, mx, redf, bcast);
  const float lo = bcast[2], hi = bcast[3];
  const bool deg = !(hi > lo);
  float meanval;

  if (deg) {
    meanval = role ? lo : -lo;
  } else {
    const float sc = (float)SNBIN / (hi - lo);
    for (int i = tid; i < SNBIN; i += 1024) hist[i] = 0u;
    __syncthreads();

    #pragma unroll 4
    for (int i = 0; i < 16; ++i) {
      const int base = i * 4096 + tid * 4;
      const float4 v4 = *reinterpret_cast<const float4*>(row + base);
      const unsigned bits = bitmap[base >> 5] >> (base & 31);
      const float vv[4] = {v4.x, v4.y, v4.z, v4.w};
      #pragma unroll
      for (int j = 0; j < 4; ++j) {
        if ((int)((bits >> j) & 1u) != role) {
          const float w = role ? vv[j] : -vv[j];
          atomicAdd(&hist[binS(w, lo, sc)], 1u);
        }
      }
    }
    __syncthreads();

    {
      unsigned b4[4]; unsigned s4 = 0;
      #pragma unroll
      for (int j = 0; j < 4; ++j) { b4[j] = hist[tid * 4 + j]; s4 += b4[j]; }
      unsigned cum = s4;
      #pragma unroll
      for (int d = 1; d < 64; d <<= 1) {
        const unsigned t = (unsigned)__shfl_up((int)cum, d, 64);
        if (lane >= d) cum += t;
      }
      if (lane == 63) wscan[wid] = cum;
      __syncthreads();
      if (tid < 16) {
        unsigned v = wscan[tid];
        #pragma unroll
        for (int d = 1; d < 16; d <<= 1) {
          const unsigned t = (unsigned)__shfl_up((int)v, d, 64);
          if (tid >= d) v += t;
        }
        wscan[tid] = v;
      }
      __syncthreads();
      const unsigned gcum = cum + (wid ? wscan[wid - 1] : 0u);
      const unsigned gprev = gcum - s4;
      if (gcum >= (unsigned)KSEL && gprev < (unsigned)KSEL) {
        unsigned run = gprev;
        #pragma unroll
        for (int j = 0; j < 4; ++j) {
          if (run + b4[j] >= (unsigned)KSEL) { bsel_s = tid * 4 + j; strict_s = run; break; }
          run += b4[j];
        }
      }
      __syncthreads();
    }
    const int B = bsel_s;
    const int need = KSEL - (int)strict_s;

    float ss = 0.f;
    #pragma unroll 4
    for (int i = 0; i < 16; ++i) {
      const int base = i * 4096 + tid * 4;
      const float4 v4 = *reinterpret_cast<const float4*>(row + base);
      const unsigned bits = bitmap[base >> 5] >> (base & 31);
      const float vv[4] = {v4.x, v4.y, v4.z, v4.w};
      #pragma unroll
      for (int j = 0; j < 4; ++j) {
        if ((int)((bits >> j) & 1u) != role) {
          const float w = role ? vv[j] : -vv[j];
          const int b = binS(w, lo, sc);
          if (b < B) ss += w;
          else if (b == B) { const int p = atomicAdd(&bcnt_s, 1); if (p < 1024) bbuf[p] = w; }
        }
      }
    }
    redB(ss, 0.f, 0.f, redf, bcast);
    const float SS = bcast[0];
    const int cnt = bcnt_s;

    if (cnt <= 1024) {
      if (wid == 0) {
        const float s = wavePeel(bbuf, cnt, need, lane);
        if (lane == 0) bsum_s = s;
      }
      __syncthreads();
    } else {
      float thr = -1e30f, accum = 0.f;
      int taken = 0;
      for (int g = 0; g < 64 && taken < need; ++g) {
        float m = 1e30f;
        for (int i = 0; i < 16; ++i) {
          const int base = i * 4096 + tid * 4;
          const float4 v4 = *reinterpret_cast<const float4*>(row + base);
          const unsigned bits = bitmap[base >> 5] >> (base & 31);
          const float vv[4] = {v4.x, v4.y, v4.z, v4.w};
          for (int j = 0; j < 4; ++j) {
            if ((int)((bits >> j) & 1u) != role) {
              const float w = role ? vv[j] : -vv[j];
              if (binS(w, lo, sc) == B && w > thr) m = fminf(m, w);
            }
          }
        }
        redB(0.f, m, 0.f, redf, bcast);
        const float M = bcast[2];
        float ce = 0.f;
        for (int i = 0; i < 16; ++i) {
          const int base = i * 4096 + tid * 4;
          const float4 v4 = *reinterpret_cast<const float4*>(row + base);
          const unsigned bits = bitmap[base >> 5] >> (base & 31);
          const float vv[4] = {v4.x, v4.y, v4.z, v4.w};
          for (int j = 0; j < 4; ++j) {
            if ((int)((bits >> j) & 1u) != role) {
              const float w = role ? vv[j] : -vv[j];
              if (w == M) ce += 1.f;
            }
          }
        }
        redB(ce, 0.f, 0.f, redf, bcast);
        const int CE = (int)bcast[0];
        const int take = (need - taken) < CE ? (need - taken) : CE;
        accum += (float)take * M;
        taken += take;
        thr = M;
      }
      if (tid == 0) bsum_s = accum;
      __syncthreads();
    }

    const float total = SS + bsum_s;
    meanval = role ? total * (1.0f / 64.0f) : -total * (1.0f / 64.0f);
  }

  if (tid == 0) {
    __hip_atomic_store(&means[role * 64 + c], meanval, __ATOMIC_RELAXED, __HIP_MEMORY_SCOPE_AGENT);
    const unsigned old = __hip_atomic_fetch_add(done, 1u, __ATOMIC_ACQ_REL, __HIP_MEMORY_SCOPE_AGENT);
    lastflag = (old == 127u) ? 1 : 0;
  }
  __syncthreads();
  if (lastflag && tid < 64) {
    const float pm = __hip_atomic_load(&means[tid], __ATOMIC_ACQUIRE, __HIP_MEMORY_SCOPE_AGENT);
    const float nm = __hip_atomic_load(&means[64 + tid], __ATOMIC_ACQUIRE, __HIP_MEMORY_SCOPE_AGENT);
    float pc = fmaxf(1.0f + pm - nm, 0.0f);
    #pragma unroll
    for (int o = 32; o; o >>= 1) pc += __shfl_down(pc, o, 64);
    if (tid == 0) out[0] = pc * (1.0f / 4096.0f);
  }
}

// ----------------------------------------------------------------------
extern "C" void kernel_launch(void* const* d_in, const int* in_sizes, int n_in,
                              void* d_out, int out_size, void* d_ws, size_t ws_size,
                              hipStream_t stream) {
  const float* x = (const float*)d_in[0];
  const int* y = (const int*)d_in[1];
  float* out = (float*)d_out;
  char* w = (char*)d_ws;
  int* counts          = (int*)(w + OFF_COUNTS);
  float* csum          = (float*)(w + OFF_CSUM);
  unsigned short* cenb = (unsigned short*)(w + OFF_CENTERS);
  float* c2            = (float*)(w + OFF_C2);
  float* means         = (float*)(w + OFF_MEANS);
  unsigned* done       = (unsigned*)(w + OFF_DONE);

  const bool big = (ws_size >= (size_t)WS_NEED);
  float* dist = (float*)(w + (big ? OFF_DIST : OFF_DIST_FB));
  unsigned* xb32 = big ? (unsigned*)(w + OFF_XB) : (unsigned*)nullptr;

  hipLaunchKernelGGL(k_init, dim3(64), dim3(256), 0, stream, counts, csum, done);
  hipLaunchKernelGGL(k_class_sums, dim3(1024), dim3(256), 0, stream, x, y, csum, counts, xb32);
  hipLaunchKernelGGL(k_centers, dim3(64), dim3(64), 0, stream, csum, counts, cenb, c2);
  if (big) {
    hipLaunchKernelGGL(k_dist_bf, dim3(N_SAMP / 128), dim3(512), 0, stream,
                       (const unsigned short*)xb32, cenb, c2, dist);
  } else {
    hipLaunchKernelGGL(k_dist_f32, dim3(N_SAMP / 128), dim3(512), 0, stream, x, cenb, c2, dist);
  }
  hipLaunchKernelGGL(k_select4, dim3(128), dim3(1024), 0, stream, dist, y, means, done, out);
}